// Round 12
// baseline (605.222 us; speedup 1.0000x reference)
//
#include <hip/hip_runtime.h>

#define G_    48
#define NPG_  128
#define NTOT_ 6144
#define D_    128
#define EPG_  4096
#define ETOT_ 196608

// element offsets into f32 d_out
#define OUT_ADJ  0ull
#define OUT_PERT 37748736ull
#define OUT_MASK 75497472ull
#define OUT_PRED 76283904ull

using short8 = __attribute__((ext_vector_type(8))) short;
using short4v = __attribute__((ext_vector_type(4))) short;
using half8  = __attribute__((ext_vector_type(8))) _Float16;
using f32x4  = __attribute__((ext_vector_type(4))) float;
using float4v = __attribute__((ext_vector_type(4))) float;

__device__ __forceinline__ short f2h(float f) {
    _Float16 h = (_Float16)f;
    return __builtin_bit_cast(short, h);
}
__device__ __forceinline__ float h2f(short s) {
    _Float16 h = __builtin_bit_cast(_Float16, s);
    return (float)h;
}
__device__ __forceinline__ float ftanh(float x) {
    float ax = fabsf(x);
    float e = __expf(-2.0f * ax);
    float r = (1.0f - e) / (1.0f + e);
    return copysignf(r, x);
}

// ---------------------------------------------------------------------------
// K1 (k_pre): heterogeneous blocks, 256 thr, 32 KB LDS.
//  [0,384)    pert: self-built u8 histogram + f64 P@A+Bp, sign -> 0/1
//  [384,432)  adj histogram -> f32 diag + fp16 adjT
//  [432,688)  weight transpose -> fp16 WT
//  [688,784)  mask + fp16 transposed x/xm (xhT/xmhT, [g][feat][node])
//  [784,2320) zero-fill rows 0..6143 of adj map (off-diagonal, NT stores)
// ---------------------------------------------------------------------------
__global__ void __launch_bounds__(256) k_pre(const int* __restrict__ ei,
                                             const float* __restrict__ x,
                                             const float* __restrict__ M,
                                             const float* __restrict__ P,
                                             const float* __restrict__ Bp,
                                             const float* __restrict__ Wa,
                                             const float* __restrict__ Wb,
                                             const float* __restrict__ Wc,
                                             float* __restrict__ out,
                                             short* __restrict__ adjT,
                                             short* __restrict__ pertT,
                                             short* __restrict__ xhT,
                                             short* __restrict__ xmhT,
                                             short* __restrict__ WT)
{
    __shared__ char sm[32768];
    const int bid = blockIdx.x, t = threadIdx.x;

    if (bid < 384) {
        // ---- pert: rebuild histogram locally (packed u8 in u32 atomics)
        unsigned int* H = (unsigned int*)sm;         // 4096 words = 16 KB
        const int g = bid >> 3;
        const int i0 = (bid & 7) * 16;
        for (int i = t; i < 4096; i += 256) H[i] = 0u;
        __syncthreads();
        const int* srcp = ei + g * EPG_;
        const int* dstp = ei + ETOT_ + g * EPG_;
        const int base = g * NPG_;
        for (int i = t; i < EPG_; i += 256) {
            int s = srcp[i] - base;
            int d = dstp[i] - base;
            int cell = s * NPG_ + d;
            atomicAdd(&H[cell >> 2], 1u << ((cell & 3) * 8));
        }
        __syncthreads();
        const unsigned char* sA = (const unsigned char*)sm;
        const int i = i0 + (t >> 4);
        const int j0 = (t & 15) * 8;
        const float* Prow = P + ((size_t)g * NPG_ + i) * NPG_;
        const float* Brow = Bp + ((size_t)g * NPG_ + i) * NPG_ + j0;
        double acc[8];
        #pragma unroll
        for (int jj = 0; jj < 8; jj++) acc[jj] = (double)Brow[jj];
        for (int k = 0; k < NPG_; k++) {
            double p = (double)Prow[k];
            const unsigned char* ar = &sA[k * NPG_ + j0];
            #pragma unroll
            for (int jj = 0; jj < 8; jj++) acc[jj] += p * (double)ar[jj];
        }
        const size_t obase = OUT_PERT + (size_t)(g * NPG_ + i) * NTOT_ + g * NPG_ + j0;
        #pragma unroll
        for (int jj = 0; jj < 8; jj++) {
            bool one = (acc[jj] > 0.0);
            out[obase + jj] = one ? 1.0f : 0.0f;
            pertT[g * NPG_ * NPG_ + (j0 + jj) * NPG_ + i] = one ? (short)0x3C00 : (short)0;
        }
    } else if (bid < 432) {
        // ---- adjacency histogram (packed u8 in u32)
        unsigned int* H = (unsigned int*)sm;
        const int g = bid - 384;
        for (int i = t; i < 4096; i += 256) H[i] = 0u;
        __syncthreads();
        const int* srcp = ei + g * EPG_;
        const int* dstp = ei + ETOT_ + g * EPG_;
        const int base = g * NPG_;
        for (int i = t; i < EPG_; i += 256) {
            int s = srcp[i] - base;
            int d = dstp[i] - base;
            int cell = s * NPG_ + d;
            atomicAdd(&H[cell >> 2], 1u << ((cell & 3) * 8));
        }
        __syncthreads();
        const unsigned char* A8 = (const unsigned char*)sm;
        for (int i = t; i < NPG_ * NPG_; i += 256) {
            int r = i >> 7, c = i & 127;
            float cnt = (float)A8[i];
            out[OUT_ADJ + (size_t)(base + r) * NTOT_ + base + c] = cnt;
            adjT[g * NPG_ * NPG_ + c * NPG_ + r] = f2h(cnt);   // exact small ints
        }
    } else if (bid < 688) {
        // ---- weight transpose + fp16 convert
        const int wtb = bid - 432;
        #pragma unroll
        for (int e = 0; e < 4; e++) {
            int idx = wtb * 1024 + e * 256 + t;
            if (idx < 65536) {                       // WaT[l][n<256][k<128] = Wa[l][k][n]
                int l = idx >> 15, r = idx & 32767;
                int n = r >> 7, k = r & 127;
                WT[idx] = f2h(Wa[l * 32768 + k * 256 + n]);
            } else if (idx < 196608) {               // WbT[l][n<256][k<256] = Wb[l][k][n]
                int j = idx - 65536;
                int l = j >> 16, r = j & 65535;
                int n = r >> 8, k = r & 255;
                WT[idx] = f2h(Wb[l * 65536 + k * 256 + n]);
            } else {                                 // WcT[l][n<128][k<256] = Wc[l][k][n]
                int j = idx - 196608;
                int l = j >> 15, r = j & 32767;
                int n = r >> 8, k = r & 255;
                WT[idx] = f2h(Wc[l * 32768 + k * 128 + n]);
            }
        }
    } else if (bid < 784) {
        // ---- mask + transposed fp16 x / x_masked: 2 blocks/graph, 64 nodes
        short* sT  = (short*)sm;                     // [128 f][64 s] = 16 KB
        short* sTm = (short*)sm + 8192;              // 16 KB
        const int b2 = bid - 688;
        const int g = b2 >> 1, half = b2 & 1;
        const size_t n0 = (size_t)g * 128 + half * 64;
        const float* xb = x + n0 * 128;
        const float* Mb = M + n0 * 128;
        float* om = out + OUT_MASK + n0 * 128;
        #pragma unroll
        for (int j = 0; j < 8; j++) {
            int i = j * 256 + t;                     // 2048 float4s = 64x128
            float4v xv = *(const float4v*)(xb + i * 4);
            float4v mv = *(const float4v*)(Mb + i * 4);
            int nl = i >> 5;
            int f0 = (i & 31) * 4;
            float4v o;
            #pragma unroll
            for (int e = 0; e < 4; e++) {
                bool pos = (mv[e] > 0.0f);
                o[e] = pos ? 1.0f : 0.0f;
                short hx = f2h(xv[e]);
                sT [(f0 + e) * 64 + nl] = hx;
                sTm[(f0 + e) * 64 + nl] = pos ? hx : (short)0;
            }
            *(float4v*)(om + i * 4) = o;
        }
        __syncthreads();
        short* dx  = xhT  + (size_t)g * 16384 + half * 64;
        short* dxm = xmhT + (size_t)g * 16384 + half * 64;
        int f = t >> 1, c0 = (t & 1) * 32;
        #pragma unroll
        for (int k = 0; k < 4; k++) {
            *(short8*)(dx  + f * 128 + c0 + k * 8) = *(short8*)&sT [f * 64 + c0 + k * 8];
            *(short8*)(dxm + f * 128 + c0 + k * 8) = *(short8*)&sTm[f * 64 + c0 + k * 8];
        }
    } else {
        // ---- zero-fill rows [0,6144) of adj map, skip diagonal block
        const int fid = bid - 784;                   // [0,1536)
        float4v* p = (float4v*)out;
        const float4v z4 = {0.f, 0.f, 0.f, 0.f};
        #pragma unroll
        for (int q = 0; q < 4; q++) {
            int rr = fid * 4 + q;                    // row in adj map
            size_t base4 = (size_t)rr * 1536;
            int gr = rr >> 7;
            int dlo = gr * 32, dhi = dlo + 32;
            #pragma unroll
            for (int it = 0; it < 6; it++) {
                int s = it * 256 + t;
                if (s < dlo || s >= dhi)
                    __builtin_nontemporal_store(z4, p + base4 + s);
            }
        }
    }
}

// ---------------------------------------------------------------------------
// k_layer<L>: 576 compute blocks (tile = (g,run), 4 row-blocks of 32 rows,
// 8 waves: 2 row-strips x 4 col-quarters) + 768 fill blocks (4 rows each,
// NT stores).
// LDS (shorts): hT [0,16384); z [16384,20480); t1/t2 [16384,24576).
// L1 fc3 writes f32 h' tile over bytes [0,16384) then block-reduces to psum.
// ---------------------------------------------------------------------------
template<int LAYER>
__global__ void __launch_bounds__(512) k_layer(
    const short* __restrict__ hTx, const short* __restrict__ hTxm,
    const short* __restrict__ hTprev,
    const short* __restrict__ adjT, const short* __restrict__ pertT,
    const short* __restrict__ WT,
    const float* __restrict__ ba, const float* __restrict__ bb, const float* __restrict__ bc,
    short* __restrict__ hTout, float* __restrict__ psum,
    float* __restrict__ out, long fillRowBase)
{
    __shared__ short S[24576]; // 48 KB
    const int bid = blockIdx.x, t = threadIdx.x;

    if (bid >= 576) {
        const int fid = bid - 576;                   // [0,768)
        float4v* p = (float4v*)out;
        const float4v z4 = {0.f, 0.f, 0.f, 0.f};
        #pragma unroll
        for (int q = 0; q < 4; q++) {
            long r = fillRowBase + (long)fid * 4 + q;   // virtual row [0,12288)
            long rr = (r >= 6144) ? r - 6144 : r;
            size_t base4 = ((r >= 6144) ? (OUT_PERT >> 2) : 0) + (size_t)rr * 1536;
            int gr = (int)(rr >> 7);
            int dlo = gr * 32, dhi = dlo + 32;
            #pragma unroll
            for (int it = 0; it < 3; it++) {
                int s = it * 512 + t;
                if (s < dlo || s >= dhi)
                    __builtin_nontemporal_store(z4, p + base4 + s);
            }
        }
        return;
    }

    const int tile = bid >> 2, rs = bid & 3;
    const int run = tile % 3, g = tile / 3;
    const int w = t >> 6, l = t & 63, lr = l & 15, lh = l >> 4;
    const int sl = (w >> 2) * 16;                    // row strip: 0 or 16
    const int cq = w & 3;                            // column quarter
    const int rowg0 = rs * 32;

    const short* hin = (LAYER == 0)
        ? ((run == 2 ? hTxm : hTx) + (size_t)g * 16384)
        : (hTprev + (size_t)tile * 16384);
    const short* am = (run == 1 ? pertT : adjT) + (size_t)g * 16384;
    const short* WaT = WT + LAYER * 32768;
    const short* WbT = WT + 65536 + LAYER * 65536;
    const short* WcT = WT + 196608 + LAYER * 32768;
    const float* baL = ba + LAYER * 256;
    const float* bbL = bb + LAYER * 256;
    const float* bcL = bc + LAYER * 128;

    // ---- stage hT (feature-major, swizzled)
    #pragma unroll
    for (int j = 0; j < 4; j++) {
        int i = j * 512 + t;
        int f = i >> 4, s0 = (i & 15) * 8;
        short8 v = *(const short8*)(hin + f * 128 + s0);
        *(short8*)&S[f * 128 + (s0 ^ ((f & 7) << 3))] = v;
    }
    __syncthreads();

    // ---- p1: z = h + A^T h   (rows = strip, cols = 2x16 per wave)
    {
        const int ar = rowg0 + sl + lr;
        short8 a0 = *(const short8*)(am + ar * 128 +  0 + lh * 8);
        short8 a1 = *(const short8*)(am + ar * 128 + 32 + lh * 8);
        short8 a2 = *(const short8*)(am + ar * 128 + 64 + lh * 8);
        short8 a3 = *(const short8*)(am + ar * 128 + 96 + lh * 8);
        #pragma unroll
        for (int nt = 0; nt < 2; nt++) {
            int col = cq * 32 + nt * 16 + lr;
            f32x4 acc = {0.f, 0.f, 0.f, 0.f};
            half8 b;
            b = __builtin_bit_cast(half8, *(const short8*)&S[col * 128 + (( 0 + lh * 8) ^ ((col & 7) << 3))]);
            acc = __builtin_amdgcn_mfma_f32_16x16x32_f16(__builtin_bit_cast(half8, a0), b, acc, 0, 0, 0);
            b = __builtin_bit_cast(half8, *(const short8*)&S[col * 128 + ((32 + lh * 8) ^ ((col & 7) << 3))]);
            acc = __builtin_amdgcn_mfma_f32_16x16x32_f16(__builtin_bit_cast(half8, a1), b, acc, 0, 0, 0);
            b = __builtin_bit_cast(half8, *(const short8*)&S[col * 128 + ((64 + lh * 8) ^ ((col & 7) << 3))]);
            acc = __builtin_amdgcn_mfma_f32_16x16x32_f16(__builtin_bit_cast(half8, a2), b, acc, 0, 0, 0);
            b = __builtin_bit_cast(half8, *(const short8*)&S[col * 128 + ((96 + lh * 8) ^ ((col & 7) << 3))]);
            acc = __builtin_amdgcn_mfma_f32_16x16x32_f16(__builtin_bit_cast(half8, a3), b, acc, 0, 0, 0);
            #pragma unroll
            for (int r = 0; r < 4; r++) {
                int zl = sl + lh * 4 + r;
                int rg = rowg0 + zl;
                float hv = h2f(S[col * 128 + (rg ^ ((col & 7) << 3))]);
                S[16384 + zl * 128 + (col ^ ((zl & 7) << 3))] = f2h(hv + acc[r]);
            }
        }
    }
    __syncthreads();

    // ---- fc1: t1(32x256) = tanh(z @ Wa + ba)   (K=128)
    {
        const int za = sl + lr;
        short8 a0 = *(const short8*)&S[16384 + za * 128 + (( 0 + lh * 8) ^ ((za & 7) << 3))];
        short8 a1 = *(const short8*)&S[16384 + za * 128 + ((32 + lh * 8) ^ ((za & 7) << 3))];
        short8 a2 = *(const short8*)&S[16384 + za * 128 + ((64 + lh * 8) ^ ((za & 7) << 3))];
        short8 a3 = *(const short8*)&S[16384 + za * 128 + ((96 + lh * 8) ^ ((za & 7) << 3))];
        __syncthreads();                              // t1 overlaps z
        #pragma unroll
        for (int nt = 0; nt < 4; nt++) {
            int col = cq * 64 + nt * 16 + lr;
            const short* wb = WaT + col * 128 + lh * 8;
            f32x4 acc = {0.f, 0.f, 0.f, 0.f};
            half8 b;
            b = __builtin_bit_cast(half8, *(const short8*)(wb +  0));
            acc = __builtin_amdgcn_mfma_f32_16x16x32_f16(__builtin_bit_cast(half8, a0), b, acc, 0, 0, 0);
            b = __builtin_bit_cast(half8, *(const short8*)(wb + 32));
            acc = __builtin_amdgcn_mfma_f32_16x16x32_f16(__builtin_bit_cast(half8, a1), b, acc, 0, 0, 0);
            b = __builtin_bit_cast(half8, *(const short8*)(wb + 64));
            acc = __builtin_amdgcn_mfma_f32_16x16x32_f16(__builtin_bit_cast(half8, a2), b, acc, 0, 0, 0);
            b = __builtin_bit_cast(half8, *(const short8*)(wb + 96));
            acc = __builtin_amdgcn_mfma_f32_16x16x32_f16(__builtin_bit_cast(half8, a3), b, acc, 0, 0, 0);
            float bv = baL[col];
            #pragma unroll
            for (int r = 0; r < 4; r++) {
                int zl = sl + lh * 4 + r;
                S[16384 + zl * 256 + (col ^ ((zl & 7) << 3))] = f2h(ftanh(acc[r] + bv));
            }
        }
    }
    __syncthreads();

    // ---- fc2: t2 = tanh(t1 @ Wb + bb)   (K=256, in place)
    {
        const int za = sl + lr;
        short8 a[8];
        #pragma unroll
        for (int ks = 0; ks < 8; ks++)
            a[ks] = *(const short8*)&S[16384 + za * 256 + ((ks * 32 + lh * 8) ^ ((za & 7) << 3))];
        __syncthreads();
        #pragma unroll
        for (int nt = 0; nt < 4; nt++) {
            int col = cq * 64 + nt * 16 + lr;
            const short* wb = WbT + col * 256 + lh * 8;
            f32x4 acc = {0.f, 0.f, 0.f, 0.f};
            #pragma unroll
            for (int ks = 0; ks < 8; ks++) {
                half8 b = __builtin_bit_cast(half8, *(const short8*)(wb + ks * 32));
                acc = __builtin_amdgcn_mfma_f32_16x16x32_f16(__builtin_bit_cast(half8, a[ks]), b, acc, 0, 0, 0);
            }
            float bv = bbL[col];
            #pragma unroll
            for (int r = 0; r < 4; r++) {
                int zl = sl + lh * 4 + r;
                S[16384 + zl * 256 + (col ^ ((zl & 7) << 3))] = f2h(ftanh(acc[r] + bv));
            }
        }
    }
    __syncthreads();

    // ---- fc3: h' = tanh(tanh(t2 @ Wc + bc))
    {
        const int za = sl + lr;
        short8 a[8];
        #pragma unroll
        for (int ks = 0; ks < 8; ks++)
            a[ks] = *(const short8*)&S[16384 + za * 256 + ((ks * 32 + lh * 8) ^ ((za & 7) << 3))];
        #pragma unroll
        for (int nt = 0; nt < 2; nt++) {
            int col = cq * 32 + nt * 16 + lr;
            const short* wb = WcT + col * 256 + lh * 8;
            f32x4 acc = {0.f, 0.f, 0.f, 0.f};
            #pragma unroll
            for (int ks = 0; ks < 8; ks++) {
                half8 b = __builtin_bit_cast(half8, *(const short8*)(wb + ks * 32));
                acc = __builtin_amdgcn_mfma_f32_16x16x32_f16(__builtin_bit_cast(half8, a[ks]), b, acc, 0, 0, 0);
            }
            float bv = bcL[col];
            if (LAYER == 0) {
                short4v hv;
                #pragma unroll
                for (int r = 0; r < 4; r++)
                    hv[r] = f2h(ftanh(ftanh(acc[r] + bv)));
                *(short4v*)(hTout + (size_t)tile * 16384 + col * 128 + rowg0 + sl + lh * 4) = hv;
            } else {
                float* F = (float*)S;                // bytes [0,16384): 32x128 f32
                #pragma unroll
                for (int r = 0; r < 4; r++) {
                    int zl = sl + lh * 4 + r;
                    F[zl * 128 + col] = ftanh(ftanh(acc[r] + bv));
                }
            }
        }
    }
    if (LAYER == 1) {
        __syncthreads();
        if (t < 128) {
            const float* F = (const float*)S;
            float s = 0.f;
            #pragma unroll 8
            for (int zl = 0; zl < 32; zl++) s += F[zl * 128 + t];
            psum[(size_t)tile * 512 + rs * 128 + t] = s;
        }
    }
}

// ---------------------------------------------------------------------------
// k_post: sum 4 partials, /128, 3-layer MLP per (g,run). 144 blocks.
// ---------------------------------------------------------------------------
__global__ void __launch_bounds__(128) k_post(
    const float* __restrict__ psum,
    const float* __restrict__ mW1, const float* __restrict__ mb1,
    const float* __restrict__ mW2, const float* __restrict__ mb2,
    const float* __restrict__ mW3, const float* __restrict__ mb3,
    float* __restrict__ out)
{
    __shared__ float aux[160];
    const int tile = blockIdx.x, t = threadIdx.x;
    const int run = tile % 3, g = tile / 3;
    const float* pp = psum + (size_t)tile * 512;
    aux[t] = (pp[t] + pp[128 + t] + pp[256 + t] + pp[384 + t]) * 0.0078125f;
    __syncthreads();
    if (t < 16) {
        float a = mb1[t];
        #pragma unroll 8
        for (int d = 0; d < 128; d++) a += aux[d] * mW1[d * 16 + t];
        aux[128 + t] = ftanh(a);
    }
    __syncthreads();
    if (t < 8) {
        float a = mb2[t];
        #pragma unroll
        for (int d = 0; d < 16; d++) a += aux[128 + d] * mW2[d * 8 + t];
        aux[144 + t] = ftanh(a);
    }
    __syncthreads();
    if (t < 2) {
        float a = mb3[t];
        #pragma unroll
        for (int d = 0; d < 8; d++) a += aux[144 + d] * mW3[d * 2 + t];
        out[OUT_PRED + (size_t)run * 96 + g * 2 + t] = ftanh(a);
    }
}

// ---------------------------------------------------------------------------
extern "C" void kernel_launch(void* const* d_in, const int* in_sizes, int n_in,
                              void* d_out, int out_size, void* d_ws, size_t ws_size,
                              hipStream_t stream)
{
    (void)in_sizes; (void)n_in; (void)out_size; (void)ws_size;

    const float* x   = (const float*)d_in[0];
    const int*   ei  = (const int*)d_in[1];
    const float* P   = (const float*)d_in[3];
    const float* Bp  = (const float*)d_in[4];
    const float* M   = (const float*)d_in[5];
    const float* Wa  = (const float*)d_in[6];
    const float* ba  = (const float*)d_in[7];
    const float* Wb  = (const float*)d_in[8];
    const float* bb  = (const float*)d_in[9];
    const float* Wc  = (const float*)d_in[10];
    const float* bc  = (const float*)d_in[11];
    const float* mW1 = (const float*)d_in[12];
    const float* mb1 = (const float*)d_in[13];
    const float* mW2 = (const float*)d_in[14];
    const float* mb2 = (const float*)d_in[15];
    const float* mW3 = (const float*)d_in[16];
    const float* mb3 = (const float*)d_in[17];
    float* out = (float*)d_out;

    char* ws = (char*)d_ws;
    short* adjT  = (short*)(ws + 0);          // 1,572,864
    short* pertT = (short*)(ws + 1572864);    // 1,572,864
    short* xhT   = (short*)(ws + 3145728);    // 1,572,864
    short* xmhT  = (short*)(ws + 4718592);    // 1,572,864
    short* WT    = (short*)(ws + 6291456);    // 524,288
    short* hT1   = (short*)(ws + 6815744);    // 4,718,592
    float* psum  = (float*)(ws + 11534336);   // 294,912

    k_pre<<<2320, 256, 0, stream>>>(ei, x, M, P, Bp, Wa, Wb, Wc, out,
                                    adjT, pertT, xhT, xmhT, WT);
    k_layer<0><<<1344, 512, 0, stream>>>(xhT, xmhT, (const short*)nullptr,
                                         adjT, pertT, WT, ba, bb, bc,
                                         hT1, psum, out, 6144L);
    k_layer<1><<<1344, 512, 0, stream>>>(xhT, xmhT, hT1,
                                         adjT, pertT, WT, ba, bb, bc,
                                         (short*)nullptr, psum, out, 9216L);
    k_post<<<144, 128, 0, stream>>>(psum, mW1, mb1, mW2, mb2, mW3, mb3, out);
}

// Round 13
// 165.668 us; speedup vs baseline: 3.6532x; 3.6532x over previous
//
#include <hip/hip_runtime.h>

#define G_    48
#define NPG_  128
#define NTOT_ 6144
#define D_    128
#define EPG_  4096
#define ETOT_ 196608

// element offsets into f32 d_out
#define OUT_ADJ  0ull
#define OUT_PERT 37748736ull
#define OUT_MASK 75497472ull
#define OUT_PRED 76283904ull

using short8 = __attribute__((ext_vector_type(8))) short;
using short4v = __attribute__((ext_vector_type(4))) short;
using half8  = __attribute__((ext_vector_type(8))) _Float16;
using f32x4  = __attribute__((ext_vector_type(4))) float;
using float4v = __attribute__((ext_vector_type(4))) float;

__device__ __forceinline__ short f2h(float f) {
    _Float16 h = (_Float16)f;
    return __builtin_bit_cast(short, h);
}
__device__ __forceinline__ float h2f(short s) {
    _Float16 h = __builtin_bit_cast(_Float16, s);
    return (float)h;
}
__device__ __forceinline__ float ftanh(float x) {
    float ax = fabsf(x);
    float e = __expf(-2.0f * ax);
    float r = (1.0f - e) / (1.0f + e);
    return copysignf(r, x);
}

// ---------------------------------------------------------------------------
// K1 (k_pre): heterogeneous blocks, 256 thr, 32 KB LDS.
//  [0,384)    pert: self-built u8 histogram + f64 P@A+Bp, sign -> 0/1
//  [384,432)  adj histogram -> f32 diag + fp16 adjT
//  [432,688)  weight transpose -> fp16 WT
//  [688,784)  mask + fp16 transposed x/xm (xhT/xmhT, [g][feat][node])
//  [784,2320) zero-fill rows 0..6143 of adj map (off-diagonal, NT stores)
// ---------------------------------------------------------------------------
__global__ void __launch_bounds__(256) k_pre(const int* __restrict__ ei,
                                             const float* __restrict__ x,
                                             const float* __restrict__ M,
                                             const float* __restrict__ P,
                                             const float* __restrict__ Bp,
                                             const float* __restrict__ Wa,
                                             const float* __restrict__ Wb,
                                             const float* __restrict__ Wc,
                                             float* __restrict__ out,
                                             short* __restrict__ adjT,
                                             short* __restrict__ pertT,
                                             short* __restrict__ xhT,
                                             short* __restrict__ xmhT,
                                             short* __restrict__ WT)
{
    __shared__ char sm[32768];
    const int bid = blockIdx.x, t = threadIdx.x;

    if (bid < 384) {
        // ---- pert: rebuild histogram locally (packed u8 in u32 atomics)
        unsigned int* H = (unsigned int*)sm;         // 4096 words = 16 KB
        const int g = bid >> 3;
        const int i0 = (bid & 7) * 16;
        for (int i = t; i < 4096; i += 256) H[i] = 0u;
        __syncthreads();
        const int* srcp = ei + g * EPG_;
        const int* dstp = ei + ETOT_ + g * EPG_;
        const int base = g * NPG_;
        for (int i = t; i < EPG_; i += 256) {
            int s = srcp[i] - base;
            int d = dstp[i] - base;
            int cell = s * NPG_ + d;
            atomicAdd(&H[cell >> 2], 1u << ((cell & 3) * 8));
        }
        __syncthreads();
        const unsigned char* sA = (const unsigned char*)sm;
        const int i = i0 + (t >> 4);
        const int j0 = (t & 15) * 8;
        const float* Prow = P + ((size_t)g * NPG_ + i) * NPG_;
        const float* Brow = Bp + ((size_t)g * NPG_ + i) * NPG_ + j0;
        double acc[8];
        #pragma unroll
        for (int jj = 0; jj < 8; jj++) acc[jj] = (double)Brow[jj];
        for (int k = 0; k < NPG_; k++) {
            double p = (double)Prow[k];
            const unsigned char* ar = &sA[k * NPG_ + j0];
            #pragma unroll
            for (int jj = 0; jj < 8; jj++) acc[jj] += p * (double)ar[jj];
        }
        const size_t obase = OUT_PERT + (size_t)(g * NPG_ + i) * NTOT_ + g * NPG_ + j0;
        #pragma unroll
        for (int jj = 0; jj < 8; jj++) {
            bool one = (acc[jj] > 0.0);
            out[obase + jj] = one ? 1.0f : 0.0f;
            pertT[g * NPG_ * NPG_ + (j0 + jj) * NPG_ + i] = one ? (short)0x3C00 : (short)0;
        }
    } else if (bid < 432) {
        // ---- adjacency histogram (packed u8 in u32)
        unsigned int* H = (unsigned int*)sm;
        const int g = bid - 384;
        for (int i = t; i < 4096; i += 256) H[i] = 0u;
        __syncthreads();
        const int* srcp = ei + g * EPG_;
        const int* dstp = ei + ETOT_ + g * EPG_;
        const int base = g * NPG_;
        for (int i = t; i < EPG_; i += 256) {
            int s = srcp[i] - base;
            int d = dstp[i] - base;
            int cell = s * NPG_ + d;
            atomicAdd(&H[cell >> 2], 1u << ((cell & 3) * 8));
        }
        __syncthreads();
        const unsigned char* A8 = (const unsigned char*)sm;
        for (int i = t; i < NPG_ * NPG_; i += 256) {
            int r = i >> 7, c = i & 127;
            float cnt = (float)A8[i];
            out[OUT_ADJ + (size_t)(base + r) * NTOT_ + base + c] = cnt;
            adjT[g * NPG_ * NPG_ + c * NPG_ + r] = f2h(cnt);   // exact small ints
        }
    } else if (bid < 688) {
        // ---- weight transpose + fp16 convert
        const int wtb = bid - 432;
        #pragma unroll
        for (int e = 0; e < 4; e++) {
            int idx = wtb * 1024 + e * 256 + t;
            if (idx < 65536) {                       // WaT[l][n<256][k<128] = Wa[l][k][n]
                int l = idx >> 15, r = idx & 32767;
                int n = r >> 7, k = r & 127;
                WT[idx] = f2h(Wa[l * 32768 + k * 256 + n]);
            } else if (idx < 196608) {               // WbT[l][n<256][k<256] = Wb[l][k][n]
                int j = idx - 65536;
                int l = j >> 16, r = j & 65535;
                int n = r >> 8, k = r & 255;
                WT[idx] = f2h(Wb[l * 65536 + k * 256 + n]);
            } else {                                 // WcT[l][n<128][k<256] = Wc[l][k][n]
                int j = idx - 196608;
                int l = j >> 15, r = j & 32767;
                int n = r >> 8, k = r & 255;
                WT[idx] = f2h(Wc[l * 32768 + k * 128 + n]);
            }
        }
    } else if (bid < 784) {
        // ---- mask + transposed fp16 x / x_masked: 2 blocks/graph, 64 nodes
        short* sT  = (short*)sm;                     // [128 f][64 s] = 16 KB
        short* sTm = (short*)sm + 8192;              // 16 KB
        const int b2 = bid - 688;
        const int g = b2 >> 1, half = b2 & 1;
        const size_t n0 = (size_t)g * 128 + half * 64;
        const float* xb = x + n0 * 128;
        const float* Mb = M + n0 * 128;
        float* om = out + OUT_MASK + n0 * 128;
        #pragma unroll
        for (int j = 0; j < 8; j++) {
            int i = j * 256 + t;                     // 2048 float4s = 64x128
            float4v xv = *(const float4v*)(xb + i * 4);
            float4v mv = *(const float4v*)(Mb + i * 4);
            int nl = i >> 5;
            int f0 = (i & 31) * 4;
            float4v o;
            #pragma unroll
            for (int e = 0; e < 4; e++) {
                bool pos = (mv[e] > 0.0f);
                o[e] = pos ? 1.0f : 0.0f;
                short hx = f2h(xv[e]);
                sT [(f0 + e) * 64 + nl] = hx;
                sTm[(f0 + e) * 64 + nl] = pos ? hx : (short)0;
            }
            *(float4v*)(om + i * 4) = o;
        }
        __syncthreads();
        short* dx  = xhT  + (size_t)g * 16384 + half * 64;
        short* dxm = xmhT + (size_t)g * 16384 + half * 64;
        int f = t >> 1, c0 = (t & 1) * 32;
        #pragma unroll
        for (int k = 0; k < 4; k++) {
            *(short8*)(dx  + f * 128 + c0 + k * 8) = *(short8*)&sT [f * 64 + c0 + k * 8];
            *(short8*)(dxm + f * 128 + c0 + k * 8) = *(short8*)&sTm[f * 64 + c0 + k * 8];
        }
    } else {
        // ---- zero-fill rows [0,6144) of adj map, skip diagonal block
        const int fid = bid - 784;                   // [0,1536)
        float4v* p = (float4v*)out;
        const float4v z4 = {0.f, 0.f, 0.f, 0.f};
        #pragma unroll
        for (int q = 0; q < 4; q++) {
            int rr = fid * 4 + q;                    // row in adj map
            size_t base4 = (size_t)rr * 1536;
            int gr = rr >> 7;
            int dlo = gr * 32, dhi = dlo + 32;
            #pragma unroll
            for (int it = 0; it < 6; it++) {
                int s = it * 256 + t;
                if (s < dlo || s >= dhi)
                    __builtin_nontemporal_store(z4, p + base4 + s);
            }
        }
    }
}

// ---------------------------------------------------------------------------
// k_layer<L>: 576 compute blocks (tile = (g,run), 4 row-blocks of 32 rows,
// 8 waves: 2 row-strips x 4 col-quarters) + 768 fill blocks (4 rows each,
// NT stores).
// LDS (shorts): hT [0,16384); z [16384,20480); t1/t2 [16384,24576).
// L1 fc3 writes f32 h' tile over bytes [0,16384) then block-reduces to psum.
// ---------------------------------------------------------------------------
template<int LAYER>
__global__ void __launch_bounds__(512) k_layer(
    const short* __restrict__ hTx, const short* __restrict__ hTxm,
    const short* __restrict__ hTprev,
    const short* __restrict__ adjT, const short* __restrict__ pertT,
    const short* __restrict__ WT,
    const float* __restrict__ ba, const float* __restrict__ bb, const float* __restrict__ bc,
    short* __restrict__ hTout, float* __restrict__ psum,
    float* __restrict__ out, long fillRowBase)
{
    __shared__ short S[24576]; // 48 KB
    const int bid = blockIdx.x, t = threadIdx.x;

    if (bid >= 576) {
        const int fid = bid - 576;                   // [0,768)
        float4v* p = (float4v*)out;
        const float4v z4 = {0.f, 0.f, 0.f, 0.f};
        #pragma unroll
        for (int q = 0; q < 4; q++) {
            long r = fillRowBase + (long)fid * 4 + q;   // virtual row [0,12288)
            long rr = (r >= 6144) ? r - 6144 : r;
            size_t base4 = ((r >= 6144) ? (OUT_PERT >> 2) : 0) + (size_t)rr * 1536;
            int gr = (int)(rr >> 7);
            int dlo = gr * 32, dhi = dlo + 32;
            #pragma unroll
            for (int it = 0; it < 3; it++) {
                int s = it * 512 + t;
                if (s < dlo || s >= dhi)
                    __builtin_nontemporal_store(z4, p + base4 + s);
            }
        }
        return;
    }

    const int tile = bid >> 2, rs = bid & 3;
    const int run = tile % 3, g = tile / 3;
    const int w = t >> 6, l = t & 63, lr = l & 15, lh = l >> 4;
    const int sl = (w >> 2) * 16;                    // row strip: 0 or 16
    const int cq = w & 3;                            // column quarter
    const int rowg0 = rs * 32;

    const short* hin = (LAYER == 0)
        ? ((run == 2 ? hTxm : hTx) + (size_t)g * 16384)
        : (hTprev + (size_t)tile * 16384);
    const short* am = (run == 1 ? pertT : adjT) + (size_t)g * 16384;
    const short* WaT = WT + LAYER * 32768;
    const short* WbT = WT + 65536 + LAYER * 65536;
    const short* WcT = WT + 196608 + LAYER * 32768;
    const float* baL = ba + LAYER * 256;
    const float* bbL = bb + LAYER * 256;
    const float* bcL = bc + LAYER * 128;

    // ---- stage hT (feature-major, swizzled)
    #pragma unroll
    for (int j = 0; j < 4; j++) {
        int i = j * 512 + t;
        int f = i >> 4, s0 = (i & 15) * 8;
        short8 v = *(const short8*)(hin + f * 128 + s0);
        *(short8*)&S[f * 128 + (s0 ^ ((f & 7) << 3))] = v;
    }
    __syncthreads();

    // ---- p1: z = h + A^T h   (rows = strip, cols = 2x16 per wave)
    {
        const int ar = rowg0 + sl + lr;
        short8 a0 = *(const short8*)(am + ar * 128 +  0 + lh * 8);
        short8 a1 = *(const short8*)(am + ar * 128 + 32 + lh * 8);
        short8 a2 = *(const short8*)(am + ar * 128 + 64 + lh * 8);
        short8 a3 = *(const short8*)(am + ar * 128 + 96 + lh * 8);
        #pragma unroll
        for (int nt = 0; nt < 2; nt++) {
            int col = cq * 32 + nt * 16 + lr;
            f32x4 acc = {0.f, 0.f, 0.f, 0.f};
            half8 b;
            b = __builtin_bit_cast(half8, *(const short8*)&S[col * 128 + (( 0 + lh * 8) ^ ((col & 7) << 3))]);
            acc = __builtin_amdgcn_mfma_f32_16x16x32_f16(__builtin_bit_cast(half8, a0), b, acc, 0, 0, 0);
            b = __builtin_bit_cast(half8, *(const short8*)&S[col * 128 + ((32 + lh * 8) ^ ((col & 7) << 3))]);
            acc = __builtin_amdgcn_mfma_f32_16x16x32_f16(__builtin_bit_cast(half8, a1), b, acc, 0, 0, 0);
            b = __builtin_bit_cast(half8, *(const short8*)&S[col * 128 + ((64 + lh * 8) ^ ((col & 7) << 3))]);
            acc = __builtin_amdgcn_mfma_f32_16x16x32_f16(__builtin_bit_cast(half8, a2), b, acc, 0, 0, 0);
            b = __builtin_bit_cast(half8, *(const short8*)&S[col * 128 + ((96 + lh * 8) ^ ((col & 7) << 3))]);
            acc = __builtin_amdgcn_mfma_f32_16x16x32_f16(__builtin_bit_cast(half8, a3), b, acc, 0, 0, 0);
            #pragma unroll
            for (int r = 0; r < 4; r++) {
                int zl = sl + lh * 4 + r;
                int rg = rowg0 + zl;
                float hv = h2f(S[col * 128 + (rg ^ ((col & 7) << 3))]);
                S[16384 + zl * 128 + (col ^ ((zl & 7) << 3))] = f2h(hv + acc[r]);
            }
        }
    }
    __syncthreads();

    // ---- fc1: t1(32x256) = tanh(z @ Wa + ba)   (K=128)
    {
        const int za = sl + lr;
        short8 a0 = *(const short8*)&S[16384 + za * 128 + (( 0 + lh * 8) ^ ((za & 7) << 3))];
        short8 a1 = *(const short8*)&S[16384 + za * 128 + ((32 + lh * 8) ^ ((za & 7) << 3))];
        short8 a2 = *(const short8*)&S[16384 + za * 128 + ((64 + lh * 8) ^ ((za & 7) << 3))];
        short8 a3 = *(const short8*)&S[16384 + za * 128 + ((96 + lh * 8) ^ ((za & 7) << 3))];
        __syncthreads();                              // t1 overlaps z
        #pragma unroll
        for (int nt = 0; nt < 4; nt++) {
            int col = cq * 64 + nt * 16 + lr;
            const short* wb = WaT + col * 128 + lh * 8;
            f32x4 acc = {0.f, 0.f, 0.f, 0.f};
            half8 b;
            b = __builtin_bit_cast(half8, *(const short8*)(wb +  0));
            acc = __builtin_amdgcn_mfma_f32_16x16x32_f16(__builtin_bit_cast(half8, a0), b, acc, 0, 0, 0);
            b = __builtin_bit_cast(half8, *(const short8*)(wb + 32));
            acc = __builtin_amdgcn_mfma_f32_16x16x32_f16(__builtin_bit_cast(half8, a1), b, acc, 0, 0, 0);
            b = __builtin_bit_cast(half8, *(const short8*)(wb + 64));
            acc = __builtin_amdgcn_mfma_f32_16x16x32_f16(__builtin_bit_cast(half8, a2), b, acc, 0, 0, 0);
            b = __builtin_bit_cast(half8, *(const short8*)(wb + 96));
            acc = __builtin_amdgcn_mfma_f32_16x16x32_f16(__builtin_bit_cast(half8, a3), b, acc, 0, 0, 0);
            float bv = baL[col];
            #pragma unroll
            for (int r = 0; r < 4; r++) {
                int zl = sl + lh * 4 + r;
                S[16384 + zl * 256 + (col ^ ((zl & 7) << 3))] = f2h(ftanh(acc[r] + bv));
            }
        }
    }
    __syncthreads();

    // ---- fc2: t2 = tanh(t1 @ Wb + bb)   (K=256, in place)
    {
        const int za = sl + lr;
        short8 a[8];
        #pragma unroll
        for (int ks = 0; ks < 8; ks++)
            a[ks] = *(const short8*)&S[16384 + za * 256 + ((ks * 32 + lh * 8) ^ ((za & 7) << 3))];
        __syncthreads();
        #pragma unroll
        for (int nt = 0; nt < 4; nt++) {
            int col = cq * 64 + nt * 16 + lr;
            const short* wb = WbT + col * 256 + lh * 8;
            f32x4 acc = {0.f, 0.f, 0.f, 0.f};
            #pragma unroll
            for (int ks = 0; ks < 8; ks++) {
                half8 b = __builtin_bit_cast(half8, *(const short8*)(wb + ks * 32));
                acc = __builtin_amdgcn_mfma_f32_16x16x32_f16(__builtin_bit_cast(half8, a[ks]), b, acc, 0, 0, 0);
            }
            float bv = bbL[col];
            #pragma unroll
            for (int r = 0; r < 4; r++) {
                int zl = sl + lh * 4 + r;
                S[16384 + zl * 256 + (col ^ ((zl & 7) << 3))] = f2h(ftanh(acc[r] + bv));
            }
        }
    }
    __syncthreads();

    // ---- fc3: h' = tanh(tanh(t2 @ Wc + bc))
    {
        const int za = sl + lr;
        short8 a[8];
        #pragma unroll
        for (int ks = 0; ks < 8; ks++)
            a[ks] = *(const short8*)&S[16384 + za * 256 + ((ks * 32 + lh * 8) ^ ((za & 7) << 3))];
        #pragma unroll
        for (int nt = 0; nt < 2; nt++) {
            int col = cq * 32 + nt * 16 + lr;
            const short* wb = WcT + col * 256 + lh * 8;
            f32x4 acc = {0.f, 0.f, 0.f, 0.f};
            #pragma unroll
            for (int ks = 0; ks < 8; ks++) {
                half8 b = __builtin_bit_cast(half8, *(const short8*)(wb + ks * 32));
                acc = __builtin_amdgcn_mfma_f32_16x16x32_f16(__builtin_bit_cast(half8, a[ks]), b, acc, 0, 0, 0);
            }
            float bv = bcL[col];
            if (LAYER == 0) {
                short4v hv;
                #pragma unroll
                for (int r = 0; r < 4; r++)
                    hv[r] = f2h(ftanh(ftanh(acc[r] + bv)));
                *(short4v*)(hTout + (size_t)tile * 16384 + col * 128 + rowg0 + sl + lh * 4) = hv;
            } else {
                float* F = (float*)S;                // bytes [0,16384): 32x128 f32
                #pragma unroll
                for (int r = 0; r < 4; r++) {
                    int zl = sl + lh * 4 + r;
                    F[zl * 128 + col] = ftanh(ftanh(acc[r] + bv));
                }
            }
        }
    }
    if (LAYER == 1) {
        __syncthreads();
        if (t < 128) {
            const float* F = (const float*)S;
            float s = 0.f;
            #pragma unroll 8
            for (int zl = 0; zl < 32; zl++) s += F[zl * 128 + t];
            psum[(size_t)tile * 512 + rs * 128 + t] = s;
        }
    }
}

// ---------------------------------------------------------------------------
// k_post: sum 4 partials, /128, 3-layer MLP per (g,run). 144 blocks.
// ---------------------------------------------------------------------------
__global__ void __launch_bounds__(128) k_post(
    const float* __restrict__ psum,
    const float* __restrict__ mW1, const float* __restrict__ mb1,
    const float* __restrict__ mW2, const float* __restrict__ mb2,
    const float* __restrict__ mW3, const float* __restrict__ mb3,
    float* __restrict__ out)
{
    __shared__ float aux[160];
    const int tile = blockIdx.x, t = threadIdx.x;
    const int run = tile % 3, g = tile / 3;
    const float* pp = psum + (size_t)tile * 512;
    aux[t] = (pp[t] + pp[128 + t] + pp[256 + t] + pp[384 + t]) * 0.0078125f;
    __syncthreads();
    if (t < 16) {
        float a = mb1[t];
        #pragma unroll 8
        for (int d = 0; d < 128; d++) a += aux[d] * mW1[d * 16 + t];
        aux[128 + t] = ftanh(a);
    }
    __syncthreads();
    if (t < 8) {
        float a = mb2[t];
        #pragma unroll
        for (int d = 0; d < 16; d++) a += aux[128 + d] * mW2[d * 8 + t];
        aux[144 + t] = ftanh(a);
    }
    __syncthreads();
    if (t < 2) {
        float a = mb3[t];
        #pragma unroll
        for (int d = 0; d < 8; d++) a += aux[144 + d] * mW3[d * 2 + t];
        out[OUT_PRED + (size_t)run * 96 + g * 2 + t] = ftanh(a);
    }
}

// ---------------------------------------------------------------------------
extern "C" void kernel_launch(void* const* d_in, const int* in_sizes, int n_in,
                              void* d_out, int out_size, void* d_ws, size_t ws_size,
                              hipStream_t stream)
{
    (void)in_sizes; (void)n_in; (void)out_size; (void)ws_size;

    const float* x   = (const float*)d_in[0];
    const int*   ei  = (const int*)d_in[1];
    const float* P   = (const float*)d_in[3];
    const float* Bp  = (const float*)d_in[4];
    const float* M   = (const float*)d_in[5];
    const float* Wa  = (const float*)d_in[6];
    const float* ba  = (const float*)d_in[7];
    const float* Wb  = (const float*)d_in[8];
    const float* bb  = (const float*)d_in[9];
    const float* Wc  = (const float*)d_in[10];
    const float* bc  = (const float*)d_in[11];
    const float* mW1 = (const float*)d_in[12];
    const float* mb1 = (const float*)d_in[13];
    const float* mW2 = (const float*)d_in[14];
    const float* mb2 = (const float*)d_in[15];
    const float* mW3 = (const float*)d_in[16];
    const float* mb3 = (const float*)d_in[17];
    float* out = (float*)d_out;

    char* ws = (char*)d_ws;
    short* adjT  = (short*)(ws + 0);          // 1,572,864
    short* pertT = (short*)(ws + 1572864);    // 1,572,864
    short* xhT   = (short*)(ws + 3145728);    // 1,572,864
    short* xmhT  = (short*)(ws + 4718592);    // 1,572,864
    short* WT    = (short*)(ws + 6291456);    // 524,288
    short* hT1   = (short*)(ws + 6815744);    // 4,718,592
    float* psum  = (float*)(ws + 11534336);   // 294,912

    k_pre<<<2320, 256, 0, stream>>>(ei, x, M, P, Bp, Wa, Wb, Wc, out,
                                    adjT, pertT, xhT, xmhT, WT);
    k_layer<0><<<1344, 512, 0, stream>>>(xhT, xmhT, (const short*)nullptr,
                                         adjT, pertT, WT, ba, bb, bc,
                                         hT1, psum, out, 6144L);
    k_layer<1><<<1344, 512, 0, stream>>>(xhT, xmhT, hT1,
                                         adjT, pertT, WT, ba, bb, bc,
                                         (short*)nullptr, psum, out, 9216L);
    k_post<<<144, 128, 0, stream>>>(psum, mW1, mb1, mW2, mb2, mW3, mb3, out);
}